// Round 9
// baseline (196.343 us; speedup 1.0000x reference)
//
#include <hip/hip_runtime.h>

// VQ-VAE vector quantizer: B=32768, K=4096, D=256 (fp32)
// out = [quantized (B*D floats), vq_loss (1 float)]
//
//  xconv : X -> fp16 (hi only), 64-row-block frag tiles into d_out (16MB, overwritten later)
//  econv : E -> NEGATED fp16 (hi only), tiled [half2][ct8][kb8] 16KB frag tiles in ws
//  en2   : en2f[k] = 0.5*||E_k||^2 exact fp32 into ws
//  dist9 : barrier-free hi-only fp16 GEMM. Block = 64 rows x ONE 2048-code half.
//          X (32KB, K=256) resident in LDS (read-only after prologue). E frags
//          stream global->register (parity prefetch, compiler-counted vmcnt).
//          4 waves = 4 code quarters; wave tile 64r x 64c, 64 phases x 16 MFMA.
//          v = 0.5||e||^2 - x.e ; per-row top-2 PER HALF (4 candidates total).
//  rescore: fp64 rescore of 4 candidates -> exact winner, gather, loss partials
//  finalize: loss = 1.25 * mean((x-q)^2)

#define B_N 32768
#define K_N 4096
#define D_N 256

typedef _Float16 f16x8 __attribute__((ext_vector_type(8)));
typedef float f32x4 __attribute__((ext_vector_type(4)));
typedef unsigned int uint4v __attribute__((ext_vector_type(4)));
typedef unsigned short u16;

// ws layout (~3.1 MB)
static constexpr size_t P_TOP2 = 0;                               // 32768*2*16 = 1 MB
static constexpr size_t P_ESW  = (size_t)B_N * 2 * 16;            // +2 MB
static constexpr size_t P_EN2  = P_ESW + (size_t)K_N * D_N * 2;   // +16 KB
static constexpr size_t P_PART = P_EN2 + (size_t)K_N * 4;         // +4 KB

__device__ __forceinline__ u16 f2h(float f) {
    _Float16 h = (_Float16)f;
    return __builtin_bit_cast(u16, h);
}

__device__ __forceinline__ void gload_lds16(const void* g, void* l) {
    __builtin_amdgcn_global_load_lds(
        (const __attribute__((address_space(1))) void*)g,
        (__attribute__((address_space(3))) void*)l, 16, 0, 0);
}

#define WAITVM(N) asm volatile("s_waitcnt vmcnt(" #N ")" ::: "memory")
#define BARRIER() __builtin_amdgcn_s_barrier()

__device__ __forceinline__ void top2_merge(float& v0, int& i0, float& v1, int& i1,
                                           float ov0, int oi0, float ov1, int oi1) {
    bool bf_ = (ov0 < v0) || (ov0 == v0 && oi0 < i0);
    float w0v = bf_ ? ov0 : v0;  int w0i = bf_ ? oi0 : i0;
    float lv  = bf_ ? v0  : ov0; int li  = bf_ ? i0  : oi0;
    float cv  = bf_ ? ov1 : v1;  int ci  = bf_ ? oi1 : i1;
    bool tl = (lv < cv) || (lv == cv && li < ci);
    v0 = w0v; i0 = w0i;
    v1 = tl ? lv : cv; i1 = tl ? li : ci;
}

// ---------- xconv: X -> fp16 hi, 64-row-block tiles ----------
// u16 index = rb*16384 + kb*2048 + rf*512 + lane*8
// row = rb*64 + rf*16 + llo ; d = kb*32 + lhi*8 + j ; lane = lhi*16+llo
__global__ void xconv_kernel(const float* __restrict__ X, u16* __restrict__ Xsw) {
    const int gid = blockIdx.x * 256 + threadIdx.x;     // B_N*32 threads
    const int row = gid >> 5;
    const int d0  = (gid & 31) << 3;
    const float4 a = *reinterpret_cast<const float4*>(X + (size_t)row * D_N + d0);
    const float4 b = *reinterpret_cast<const float4*>(X + (size_t)row * D_N + d0 + 4);
    float f[8] = {a.x, a.y, a.z, a.w, b.x, b.y, b.z, b.w};
    unsigned hi[8];
    #pragma unroll
    for (int j = 0; j < 8; ++j) hi[j] = f2h(f[j]);
    const int rb = row >> 6, rr = row & 63, rf = rr >> 4, llo = rr & 15;
    const int kb = d0 >> 5, lhi = (d0 & 31) >> 3, lane = lhi * 16 + llo;
    size_t base = (size_t)rb * 16384 + (size_t)kb * 2048 + (size_t)rf * 512 + (size_t)lane * 8;
    uint4v hv;
    hv.x = hi[0] | (hi[1] << 16); hv.y = hi[2] | (hi[3] << 16);
    hv.z = hi[4] | (hi[5] << 16); hv.w = hi[6] | (hi[7] << 16);
    *reinterpret_cast<uint4v*>(Xsw + base) = hv;
}

// ---------- econv: E -> negated fp16 hi, tiled [h2][ct8][kb8] 16KB tiles ----------
// u16 index = (((h*8+ct)*8+kb)*16 + cf)*512 + lane*8
// h = code>>11, ct = (code>>8)&7, cf = (code>>4)&15, llo = code&15
__global__ void econv_kernel(const float* __restrict__ E, u16* __restrict__ Esw) {
    const int gid = blockIdx.x * 256 + threadIdx.x;     // K_N*32 threads
    const int code = gid >> 5;
    const int d0  = (gid & 31) << 3;
    const float4 a = *reinterpret_cast<const float4*>(E + (size_t)code * D_N + d0);
    const float4 b = *reinterpret_cast<const float4*>(E + (size_t)code * D_N + d0 + 4);
    float f[8] = {a.x, a.y, a.z, a.w, b.x, b.y, b.z, b.w};
    unsigned hi[8];
    #pragma unroll
    for (int j = 0; j < 8; ++j) hi[j] = f2h(-f[j]);
    const int h = code >> 11, ct = (code >> 8) & 7, cf = (code >> 4) & 15, llo = code & 15;
    const int kb = d0 >> 5, lhi = (d0 & 31) >> 3, lane = lhi * 16 + llo;
    size_t base = ((size_t)(((h * 8 + ct) * 8 + kb) * 16 + cf)) * 512 + (size_t)lane * 8;
    uint4v hv;
    hv.x = hi[0] | (hi[1] << 16); hv.y = hi[2] | (hi[3] << 16);
    hv.z = hi[4] | (hi[5] << 16); hv.w = hi[6] | (hi[7] << 16);
    *reinterpret_cast<uint4v*>(Esw + base) = hv;
}

// ---------- en2: exact fp32 0.5||e||^2 ----------
__global__ void en2_kernel(const float* __restrict__ E, float* __restrict__ en2f) {
    const int gtid = blockIdx.x * blockDim.x + threadIdx.x;
    const int code = gtid >> 6;
    const int lane = threadIdx.x & 63;
    if (code >= K_N) return;
    const float4 v = *reinterpret_cast<const float4*>(E + (size_t)code * D_N + lane * 4);
    double s = (double)v.x * v.x + (double)v.y * v.y + (double)v.z * v.z + (double)v.w * v.w;
    #pragma unroll
    for (int o = 32; o; o >>= 1) s += __shfl_xor(s, o, 64);
    if (lane == 0) en2f[code] = (float)(0.5 * s);
}

// ---------- dist9: barrier-free hi-only X-resident GEMM, E global->reg ----------
// 1024 blocks (rb = bid>>1 in 0..511, h = bid&1), 256 thr = 4 waves (wc quarters),
// wave tile 64 rows x 64 codes. LDS 32768 B: X[kb8][rf4][lane64][8]u16 (read-only).
__launch_bounds__(256, 2)
__global__ void dist9_kernel(const char* __restrict__ Xsw, const char* __restrict__ Esw,
                             const float* __restrict__ en2f, float4* __restrict__ top2) {
    __shared__ __align__(16) char lds[32768];
    const int tid  = threadIdx.x;
    const int lane = tid & 63;
    const int wid  = tid >> 6;          // 0..3
    const int wc   = wid;               // code quarter within the 256-code phase tile
    const int llo  = lane & 15, lhi = lane >> 4;
    const int rb = blockIdx.x >> 1;     // 0..511 (64-row group)
    const int h  = blockIdx.x & 1;      // code half

    const char* xb = Xsw + (size_t)rb * 32768;
    // per-wave E fragment base: phase p (ct*8+kb), frag j at ep + p*16384 + j*1024
    const char* ep = Esw + (size_t)h * 1048576 + (size_t)(wc * 4) * 1024 + (size_t)lane * 16;
    const int cbase = h * 2048;

    float tv0[16], tv1[16];
    int   tpk[16];
    #pragma unroll
    for (int s = 0; s < 16; ++s) { tv0[s] = 3.4e38f; tv1[s] = 3.4e38f; tpk[s] = -1; }

    f32x4 acc[4][4];
    #pragma unroll
    for (int i = 0; i < 4; ++i)
        #pragma unroll
        for (int j = 0; j < 4; ++j) acc[i][j] = (f32x4){0.f, 0.f, 0.f, 0.f};

    // prologue: X to LDS (32KB), first E phase to regs, en2 for ctile 0
    #pragma unroll
    for (int it = 0; it < 8; ++it)
        gload_lds16(xb + it * 4096 + tid * 16, lds + it * 4096 + wid * 1024);

    f16x8 bv[2][4];
    #pragma unroll
    for (int j = 0; j < 4; ++j)
        bv[0][j] = *reinterpret_cast<const f16x8*>(ep + j * 1024);
    float ena[4], enb[4];
    #pragma unroll
    for (int j = 0; j < 4; ++j) ena[j] = en2f[cbase + (wc * 4 + j) * 16 + llo];

    WAITVM(0);      // X resident (also drains bv loads)
    BARRIER();      // the ONLY block-wide barrier before the merge

    const f16x8* LX = reinterpret_cast<const f16x8*>(lds);

    for (int ct = 0; ct < 8; ++ct) {
        #pragma unroll
        for (int kb = 0; kb < 8; ++kb) {
            const int p = ct * 8 + kb;
            // prefetch phase p+1 E frags into the other parity buffer
            if (p < 63) {
                #pragma unroll
                for (int j = 0; j < 4; ++j)
                    bv[(kb + 1) & 1][j] = *reinterpret_cast<const f16x8*>(
                        ep + (size_t)(p + 1) * 16384 + j * 1024);
            }
            if (kb == 6 && ct < 7) {        // prefetch next ctile's en2
                #pragma unroll
                for (int j = 0; j < 4; ++j)
                    enb[j] = en2f[cbase + (ct + 1) * 256 + (wc * 4 + j) * 16 + llo];
            }

            __builtin_amdgcn_s_setprio(1);
            f16x8 av[4];
            #pragma unroll
            for (int i = 0; i < 4; ++i)
                av[i] = LX[(kb * 4 + i) * 64 + lane];
            #pragma unroll
            for (int i = 0; i < 4; ++i)
                #pragma unroll
                for (int j = 0; j < 4; ++j)
                    acc[i][j] = __builtin_amdgcn_mfma_f32_16x16x32_f16(
                        av[i], bv[kb & 1][j], acc[i][j], 0, 0, 0);
            __builtin_amdgcn_s_setprio(0);

            if (kb == 7) {
                // epilogue for ctile ct: v = 0.5||e||^2 - x.e ; per-lane top-2 update
                #pragma unroll
                for (int j = 0; j < 4; ++j) {
                    const int idx = cbase + ct * 256 + (wc * 4 + j) * 16 + llo;
                    const float en = ena[j];
                    #pragma unroll
                    for (int i = 0; i < 4; ++i) {
                        #pragma unroll
                        for (int r = 0; r < 4; ++r) {
                            const float v = en + acc[i][j][r];
                            const int s = i * 4 + r;
                            const bool c0 = v < tv0[s];
                            const bool c1 = v < tv1[s];
                            const int pk = tpk[s];
                            const int pkA = (pk << 16) | idx;
                            const int pkB = (idx << 16) | (pk & 0xffff);
                            tv1[s] = c0 ? tv0[s] : (c1 ? v : tv1[s]);
                            tv0[s] = c0 ? v : tv0[s];
                            tpk[s] = c0 ? pkA : (c1 ? pkB : pk);
                        }
                    }
                }
                #pragma unroll
                for (int i = 0; i < 4; ++i)
                    #pragma unroll
                    for (int j = 0; j < 4; ++j) acc[i][j] = (f32x4){0.f, 0.f, 0.f, 0.f};
                #pragma unroll
                for (int j = 0; j < 4; ++j) ena[j] = enb[j];
            }
        }
    }

    // merge the 16 column-lanes (llo) via shfl butterfly
    #pragma unroll
    for (int m = 1; m <= 8; m <<= 1) {
        #pragma unroll
        for (int s = 0; s < 16; ++s) {
            float ov0 = __shfl_xor(tv0[s], m, 64);
            float ov1 = __shfl_xor(tv1[s], m, 64);
            int   opk = __shfl_xor(tpk[s], m, 64);
            float v0 = tv0[s], v1 = tv1[s];
            int i0 = tpk[s] & 0xffff, i1 = (tpk[s] >> 16) & 0xffff;
            top2_merge(v0, i0, v1, i1, ov0, opk & 0xffff, ov1, (opk >> 16) & 0xffff);
            tv0[s] = v0; tv1[s] = v1; tpk[s] = (i1 << 16) | i0;
        }
    }

    __syncthreads();
    float4* M = reinterpret_cast<float4*>(lds);   // [64 rows][4 wc] (reuses X region)
    if (llo == 0) {
        #pragma unroll
        for (int i = 0; i < 4; ++i)
            #pragma unroll
            for (int r = 0; r < 4; ++r) {
                const int rowl = i * 16 + lhi * 4 + r;
                const int s = i * 4 + r;
                M[rowl * 4 + wc] = make_float4(tv0[s], __int_as_float(tpk[s] & 0xffff),
                                               tv1[s], __int_as_float((tpk[s] >> 16) & 0xffff));
            }
    }
    __syncthreads();
    if (tid < 64) {
        float4 A4 = M[tid * 4 + 0];
        float v0 = A4.x, v1 = A4.z;
        int i0 = __float_as_int(A4.y), i1 = __float_as_int(A4.w);
        #pragma unroll
        for (int w = 1; w < 4; ++w) {
            float4 Bw = M[tid * 4 + w];
            top2_merge(v0, i0, v1, i1, Bw.x, __float_as_int(Bw.y), Bw.z, __float_as_int(Bw.w));
        }
        top2[(size_t)(rb * 64 + tid) * 2 + h] =
            make_float4(v0, __int_as_float(i0), v1, __int_as_float(i1));
    }
}

// ---------- rescore: fp64 rescore of 4 candidates (2 per half) ----------
__global__ void rescore_kernel(const float* __restrict__ X, const float* __restrict__ E,
                               const float4* __restrict__ top2, float* __restrict__ out,
                               double* __restrict__ partials) {
    const int lane = threadIdx.x & 63;
    const int wid  = (blockIdx.x * blockDim.x + threadIdx.x) >> 6;
    const int nw   = (gridDim.x * blockDim.x) >> 6;
    double wloc = 0.0;

    for (int row = wid; row < B_N; row += nw) {
        float4 t0 = top2[(size_t)row * 2 + 0];
        float4 t1 = top2[(size_t)row * 2 + 1];
        int cand[4] = { __float_as_int(t0.y), __float_as_int(t0.w),
                        __float_as_int(t1.y), __float_as_int(t1.w) };
        const float4 xv = *reinterpret_cast<const float4*>(X + (size_t)row * D_N + lane * 4);

        double bestd = 1e300; int besti = 0x7fffffff;
        float4 beste = make_float4(0.f, 0.f, 0.f, 0.f);
        #pragma unroll
        for (int c = 0; c < 4; ++c) {
            const int k = cand[c];
            const float4 ev = *reinterpret_cast<const float4*>(E + (size_t)k * D_N + lane * 4);
            double dx = (double)xv.x - (double)ev.x;
            double dy = (double)xv.y - (double)ev.y;
            double dz = (double)xv.z - (double)ev.z;
            double dw = (double)xv.w - (double)ev.w;
            double s = dx * dx + dy * dy + dz * dz + dw * dw;
            #pragma unroll
            for (int o = 32; o; o >>= 1) s += __shfl_xor(s, o, 64);
            if (s < bestd || (s == bestd && k < besti)) { bestd = s; besti = k; beste = ev; }
        }
        *reinterpret_cast<float4*>(out + (size_t)row * D_N + lane * 4) = beste;
        wloc += bestd;
    }

    __shared__ double bsum[8];
    const int widx = threadIdx.x >> 6;
    if (lane == 0) bsum[widx] = wloc;
    __syncthreads();
    if (threadIdx.x == 0) {
        double s = 0.0;
        for (int w = 0; w < (int)(blockDim.x >> 6); ++w) s += bsum[w];
        partials[blockIdx.x] = s;
    }
}

__global__ void finalize_kernel(const double* __restrict__ partials, int n,
                                float* __restrict__ loss_out) {
    __shared__ double sm[256];
    double s = 0.0;
    for (int i = threadIdx.x; i < n; i += 256) s += partials[i];
    sm[threadIdx.x] = s;
    __syncthreads();
    for (int st = 128; st; st >>= 1) {
        if (threadIdx.x < st) sm[threadIdx.x] += sm[threadIdx.x + st];
        __syncthreads();
    }
    if (threadIdx.x == 0)
        *loss_out = (float)(1.25 * sm[0] / (double)((size_t)B_N * D_N));
}

extern "C" void kernel_launch(void* const* d_in, const int* in_sizes, int n_in,
                              void* d_out, int out_size, void* d_ws, size_t ws_size,
                              hipStream_t stream) {
    const float* X = (const float*)d_in[0];
    const float* E = (const float*)d_in[1];
    float* out = (float*)d_out;
    char* ws = (char*)d_ws;

    u16*    Xsw      = (u16*)d_out;          // 16 MiB scratch in d_out (overwritten by rescore)
    float4* top2     = (float4*)(ws + P_TOP2);
    u16*    Esw      = (u16*)(ws + P_ESW);
    float*  en2f     = (float*)(ws + P_EN2);
    double* partials = (double*)(ws + P_PART);

    xconv_kernel<<<(B_N * 32) / 256, 256, 0, stream>>>(X, Xsw);
    econv_kernel<<<(K_N * 32) / 256, 256, 0, stream>>>(E, Esw);
    en2_kernel<<<K_N / 4, 256, 0, stream>>>(E, en2f);
    dist9_kernel<<<B_N / 64 * 2, 256, 0, stream>>>(
        (const char*)Xsw, (const char*)Esw, en2f, top2);
    rescore_kernel<<<512, 256, 0, stream>>>(X, E, top2, out, partials);
    finalize_kernel<<<1, 256, 0, stream>>>(partials, 512, out + (size_t)B_N * D_N);
}

// Round 10
// 162.267 us; speedup vs baseline: 1.2100x; 1.2100x over previous
//
#include <hip/hip_runtime.h>

// VQ-VAE vector quantizer: B=32768, K=4096, D=256 (fp32)
// out = [quantized (B*D floats), vq_loss (1 float)]
//
//  xconv : X -> fp16 (hi only), 64-row-block frag tiles into d_out (16MB, overwritten later)
//  econv : E -> NEGATED fp16 (hi only), per-(ct,q,kb) 4KB frag tiles in ws
//  en2   : en2f[k] = 0.5*||E_k||^2 exact fp32 into ws
//  dist10: barrier-free hi-only GEMM. Block = 64 rows x 4096 codes, 4 waves own
//          DISTINCT 64-code columns (no duplicate E reads). X (32KB) + en2 (16KB)
//          LDS-resident; E staged WAVE-PRIVATE via global_load_lds (4KB dbuf/wave,
//          vmcnt(4) counted, no barriers). 128 phases (16 ct x 8 kb) x 16 MFMA.
//          v = 0.5||e||^2 - x.e ; per-row top-2 per wave-pair (4 candidates).
//  rescore: fp64 rescore of 4 candidates -> exact winner, gather, loss partials
//  finalize: loss = 1.25 * mean((x-q)^2)

#define B_N 32768
#define K_N 4096
#define D_N 256

typedef _Float16 f16x8 __attribute__((ext_vector_type(8)));
typedef float f32x4 __attribute__((ext_vector_type(4)));
typedef unsigned int uint4v __attribute__((ext_vector_type(4)));
typedef unsigned short u16;

// ws layout (~3.1 MB)
static constexpr size_t P_TOP2 = 0;                               // 32768*2*16 = 1 MB
static constexpr size_t P_ESW  = (size_t)B_N * 2 * 16;            // +2 MB
static constexpr size_t P_EN2  = P_ESW + (size_t)K_N * D_N * 2;   // +16 KB
static constexpr size_t P_PART = P_EN2 + (size_t)K_N * 4;         // +4 KB

__device__ __forceinline__ u16 f2h(float f) {
    _Float16 h = (_Float16)f;
    return __builtin_bit_cast(u16, h);
}

__device__ __forceinline__ void gload_lds16(const void* g, void* l) {
    __builtin_amdgcn_global_load_lds(
        (const __attribute__((address_space(1))) void*)g,
        (__attribute__((address_space(3))) void*)l, 16, 0, 0);
}

#define WAITVM(N) asm volatile("s_waitcnt vmcnt(" #N ")" ::: "memory")
#define BARRIER() __builtin_amdgcn_s_barrier()

__device__ __forceinline__ void top2_merge(float& v0, int& i0, float& v1, int& i1,
                                           float ov0, int oi0, float ov1, int oi1) {
    bool bf_ = (ov0 < v0) || (ov0 == v0 && oi0 < i0);
    float w0v = bf_ ? ov0 : v0;  int w0i = bf_ ? oi0 : i0;
    float lv  = bf_ ? v0  : ov0; int li  = bf_ ? i0  : oi0;
    float cv  = bf_ ? ov1 : v1;  int ci  = bf_ ? oi1 : i1;
    bool tl = (lv < cv) || (lv == cv && li < ci);
    v0 = w0v; i0 = w0i;
    v1 = tl ? lv : cv; i1 = tl ? li : ci;
}

// ---------- xconv: X -> fp16 hi, 64-row-block tiles ----------
// u16 index = rb*16384 + kb*2048 + rf*512 + lane*8
// row = rb*64 + rf*16 + llo ; d = kb*32 + lhi*8 + j ; lane = lhi*16+llo
__global__ void xconv_kernel(const float* __restrict__ X, u16* __restrict__ Xsw) {
    const int gid = blockIdx.x * 256 + threadIdx.x;     // B_N*32 threads
    const int row = gid >> 5;
    const int d0  = (gid & 31) << 3;
    const float4 a = *reinterpret_cast<const float4*>(X + (size_t)row * D_N + d0);
    const float4 b = *reinterpret_cast<const float4*>(X + (size_t)row * D_N + d0 + 4);
    float f[8] = {a.x, a.y, a.z, a.w, b.x, b.y, b.z, b.w};
    unsigned hi[8];
    #pragma unroll
    for (int j = 0; j < 8; ++j) hi[j] = f2h(f[j]);
    const int rb = row >> 6, rr = row & 63, rf = rr >> 4, llo = rr & 15;
    const int kb = d0 >> 5, lhi = (d0 & 31) >> 3, lane = lhi * 16 + llo;
    size_t base = (size_t)rb * 16384 + (size_t)kb * 2048 + (size_t)rf * 512 + (size_t)lane * 8;
    uint4v hv;
    hv.x = hi[0] | (hi[1] << 16); hv.y = hi[2] | (hi[3] << 16);
    hv.z = hi[4] | (hi[5] << 16); hv.w = hi[6] | (hi[7] << 16);
    *reinterpret_cast<uint4v*>(Xsw + base) = hv;
}

// ---------- econv: E -> negated fp16 hi, per-(ct,q,kb) 4KB tiles ----------
// code = ct*256 + q*64 + cf*16 + llo ; u16 index = (((ct*4+q)*8+kb)*4 + cf)*512 + lane*8
__global__ void econv_kernel(const float* __restrict__ E, u16* __restrict__ Esw) {
    const int gid = blockIdx.x * 256 + threadIdx.x;     // K_N*32 threads
    const int code = gid >> 5;
    const int d0  = (gid & 31) << 3;
    const float4 a = *reinterpret_cast<const float4*>(E + (size_t)code * D_N + d0);
    const float4 b = *reinterpret_cast<const float4*>(E + (size_t)code * D_N + d0 + 4);
    float f[8] = {a.x, a.y, a.z, a.w, b.x, b.y, b.z, b.w};
    unsigned hi[8];
    #pragma unroll
    for (int j = 0; j < 8; ++j) hi[j] = f2h(-f[j]);
    const int ct = code >> 8, q = (code >> 6) & 3, cf = (code >> 4) & 3, llo = code & 15;
    const int kb = d0 >> 5, lhi = (d0 & 31) >> 3, lane = lhi * 16 + llo;
    size_t base = ((size_t)(((ct * 4 + q) * 8 + kb) * 4 + cf)) * 512 + (size_t)lane * 8;
    uint4v hv;
    hv.x = hi[0] | (hi[1] << 16); hv.y = hi[2] | (hi[3] << 16);
    hv.z = hi[4] | (hi[5] << 16); hv.w = hi[6] | (hi[7] << 16);
    *reinterpret_cast<uint4v*>(Esw + base) = hv;
}

// ---------- en2: exact fp32 0.5||e||^2 ----------
__global__ void en2_kernel(const float* __restrict__ E, float* __restrict__ en2f) {
    const int gtid = blockIdx.x * blockDim.x + threadIdx.x;
    const int code = gtid >> 6;
    const int lane = threadIdx.x & 63;
    if (code >= K_N) return;
    const float4 v = *reinterpret_cast<const float4*>(E + (size_t)code * D_N + lane * 4);
    double s = (double)v.x * v.x + (double)v.y * v.y + (double)v.z * v.z + (double)v.w * v.w;
    #pragma unroll
    for (int o = 32; o; o >>= 1) s += __shfl_xor(s, o, 64);
    if (lane == 0) en2f[code] = (float)(0.5 * s);
}

// ---------- dist10: barrier-free, X+en2 LDS-resident, E wave-private staged ----------
// 512 blocks, 256 thr = 4 waves (q = code quarter), wave tile 64 rows x 64 codes.
// LDS 81920 B: X[kb8][rf4][lane64][8]u16 @0 (32KB) ;
//              E stage @32768: wave q at +q*8192, parity buf 4KB each ;
//              en2 fp32[4096] @65536 (16KB).
__launch_bounds__(256, 2)
__global__ void dist10_kernel(const char* __restrict__ Xsw, const char* __restrict__ Esw,
                              const float* __restrict__ en2f, float4* __restrict__ top2) {
    __shared__ __align__(16) char lds[81920];
    const int tid  = threadIdx.x;
    const int lane = tid & 63;
    const int wid  = tid >> 6;          // 0..3 = code quarter q
    const int llo  = lane & 15, lhi = lane >> 4;
    const int rb = blockIdx.x;          // 0..511 (64-row group)

    const char* xb = Xsw + (size_t)rb * 32768;
    char* ldsE = lds + 32768 + wid * 8192;

    auto STAGE_E = [&](int p) {   // stage 4KB tile (ct=p>>3, q=wid, kb=p&7) into parity p&1
        const char* es = Esw + ((size_t)(((p >> 3) * 4 + wid) * 8 + (p & 7))) * 4096;
        char* lb = ldsE + (p & 1) * 4096;
        gload_lds16(es + lane * 16,        lb);
        gload_lds16(es + 1024 + lane * 16, lb + 1024);
        gload_lds16(es + 2048 + lane * 16, lb + 2048);
        gload_lds16(es + 3072 + lane * 16, lb + 3072);
    };

    float tv0[16], tv1[16];
    int   tpk[16];
    #pragma unroll
    for (int s = 0; s < 16; ++s) { tv0[s] = 3.4e38f; tv1[s] = 3.4e38f; tpk[s] = -1; }

    f32x4 acc[4][4];
    #pragma unroll
    for (int i = 0; i < 4; ++i)
        #pragma unroll
        for (int j = 0; j < 4; ++j) acc[i][j] = (f32x4){0.f, 0.f, 0.f, 0.f};

    // prologue: X (32KB) + en2 table (16KB) to LDS, first E tile wave-private
    #pragma unroll
    for (int it = 0; it < 8; ++it)
        gload_lds16(xb + it * 4096 + tid * 16, lds + it * 4096 + wid * 1024);
    const char* en2c = reinterpret_cast<const char*>(en2f);
    #pragma unroll
    for (int it = 0; it < 4; ++it)
        gload_lds16(en2c + it * 4096 + tid * 16, lds + 65536 + it * 4096 + wid * 1024);
    STAGE_E(0);
    WAITVM(0);
    BARRIER();      // X + en2 visible to all waves; E tile 0 ready (wave-private)

    const f16x8* LX = reinterpret_cast<const f16x8*>(lds);
    const float* ENL = reinterpret_cast<const float*>(lds + 65536);

    for (int ct = 0; ct < 16; ++ct) {
        #pragma unroll
        for (int kb = 0; kb < 8; ++kb) {
            const int p = ct * 8 + kb;
            if (kb < 7) {
                STAGE_E(p + 1);
                WAITVM(4);          // drain stage(p), leave stage(p+1) in flight
            } else if (ct < 15) {
                STAGE_E(p + 1);
                WAITVM(4);
            } else {
                WAITVM(0);          // last phase
            }

            f16x8 ev[4];
            #pragma unroll
            for (int j = 0; j < 4; ++j)
                ev[j] = *reinterpret_cast<const f16x8*>(
                    ldsE + (p & 1) * 4096 + j * 1024 + lane * 16);

            __builtin_amdgcn_s_setprio(1);
            f16x8 av[4];
            #pragma unroll
            for (int i = 0; i < 4; ++i)
                av[i] = LX[(kb * 4 + i) * 64 + lane];
            #pragma unroll
            for (int i = 0; i < 4; ++i)
                #pragma unroll
                for (int j = 0; j < 4; ++j)
                    acc[i][j] = __builtin_amdgcn_mfma_f32_16x16x32_f16(
                        av[i], ev[j], acc[i][j], 0, 0, 0);
            __builtin_amdgcn_s_setprio(0);

            if (kb == 7) {
                // epilogue for ctile ct: v = 0.5||e||^2 - x.e ; per-lane top-2 update
                #pragma unroll
                for (int j = 0; j < 4; ++j) {
                    const int idx = ct * 256 + wid * 64 + j * 16 + llo;
                    const float en = ENL[idx];
                    #pragma unroll
                    for (int i = 0; i < 4; ++i) {
                        #pragma unroll
                        for (int r = 0; r < 4; ++r) {
                            const float v = en + acc[i][j][r];
                            const int s = i * 4 + r;
                            const bool c0 = v < tv0[s];
                            const bool c1 = v < tv1[s];
                            const int pk = tpk[s];
                            const int pkA = (pk << 16) | idx;
                            const int pkB = (idx << 16) | (pk & 0xffff);
                            tv1[s] = c0 ? tv0[s] : (c1 ? v : tv1[s]);
                            tv0[s] = c0 ? v : tv0[s];
                            tpk[s] = c0 ? pkA : (c1 ? pkB : pk);
                        }
                    }
                }
                #pragma unroll
                for (int i = 0; i < 4; ++i)
                    #pragma unroll
                    for (int j = 0; j < 4; ++j) acc[i][j] = (f32x4){0.f, 0.f, 0.f, 0.f};
            }
        }
    }

    // merge the 16 column-lanes (llo) via shfl butterfly
    #pragma unroll
    for (int m = 1; m <= 8; m <<= 1) {
        #pragma unroll
        for (int s = 0; s < 16; ++s) {
            float ov0 = __shfl_xor(tv0[s], m, 64);
            float ov1 = __shfl_xor(tv1[s], m, 64);
            int   opk = __shfl_xor(tpk[s], m, 64);
            float v0 = tv0[s], v1 = tv1[s];
            int i0 = tpk[s] & 0xffff, i1 = (tpk[s] >> 16) & 0xffff;
            top2_merge(v0, i0, v1, i1, ov0, opk & 0xffff, ov1, (opk >> 16) & 0xffff);
            tv0[s] = v0; tv1[s] = v1; tpk[s] = (i1 << 16) | i0;
        }
    }

    __syncthreads();
    float4* M = reinterpret_cast<float4*>(lds);   // [64 rows][4 q] (reuses X region)
    if (llo == 0) {
        #pragma unroll
        for (int i = 0; i < 4; ++i)
            #pragma unroll
            for (int r = 0; r < 4; ++r) {
                const int rowl = i * 16 + lhi * 4 + r;
                const int s = i * 4 + r;
                M[rowl * 4 + wid] = make_float4(tv0[s], __int_as_float(tpk[s] & 0xffff),
                                                tv1[s], __int_as_float((tpk[s] >> 16) & 0xffff));
            }
    }
    __syncthreads();
    if (tid < 64) {
        // pairwise merge: waves 0+1 -> entry 0, waves 2+3 -> entry 1
        #pragma unroll
        for (int h = 0; h < 2; ++h) {
            float4 A4 = M[tid * 4 + 2 * h], B4 = M[tid * 4 + 2 * h + 1];
            float v0 = A4.x, v1 = A4.z;
            int i0 = __float_as_int(A4.y), i1 = __float_as_int(A4.w);
            top2_merge(v0, i0, v1, i1, B4.x, __float_as_int(B4.y), B4.z, __float_as_int(B4.w));
            top2[(size_t)(rb * 64 + tid) * 2 + h] =
                make_float4(v0, __int_as_float(i0), v1, __int_as_float(i1));
        }
    }
}

// ---------- rescore: fp64 rescore of 4 candidates (2 per wave-pair) ----------
__global__ void rescore_kernel(const float* __restrict__ X, const float* __restrict__ E,
                               const float4* __restrict__ top2, float* __restrict__ out,
                               double* __restrict__ partials) {
    const int lane = threadIdx.x & 63;
    const int wid  = (blockIdx.x * blockDim.x + threadIdx.x) >> 6;
    const int nw   = (gridDim.x * blockDim.x) >> 6;
    double wloc = 0.0;

    for (int row = wid; row < B_N; row += nw) {
        float4 t0 = top2[(size_t)row * 2 + 0];
        float4 t1 = top2[(size_t)row * 2 + 1];
        int cand[4] = { __float_as_int(t0.y), __float_as_int(t0.w),
                        __float_as_int(t1.y), __float_as_int(t1.w) };
        const float4 xv = *reinterpret_cast<const float4*>(X + (size_t)row * D_N + lane * 4);

        double bestd = 1e300; int besti = 0x7fffffff;
        float4 beste = make_float4(0.f, 0.f, 0.f, 0.f);
        #pragma unroll
        for (int c = 0; c < 4; ++c) {
            const int k = cand[c];
            const float4 ev = *reinterpret_cast<const float4*>(E + (size_t)k * D_N + lane * 4);
            double dx = (double)xv.x - (double)ev.x;
            double dy = (double)xv.y - (double)ev.y;
            double dz = (double)xv.z - (double)ev.z;
            double dw = (double)xv.w - (double)ev.w;
            double s = dx * dx + dy * dy + dz * dz + dw * dw;
            #pragma unroll
            for (int o = 32; o; o >>= 1) s += __shfl_xor(s, o, 64);
            if (s < bestd || (s == bestd && k < besti)) { bestd = s; besti = k; beste = ev; }
        }
        *reinterpret_cast<float4*>(out + (size_t)row * D_N + lane * 4) = beste;
        wloc += bestd;
    }

    __shared__ double bsum[8];
    const int widx = threadIdx.x >> 6;
    if (lane == 0) bsum[widx] = wloc;
    __syncthreads();
    if (threadIdx.x == 0) {
        double s = 0.0;
        for (int w = 0; w < (int)(blockDim.x >> 6); ++w) s += bsum[w];
        partials[blockIdx.x] = s;
    }
}

__global__ void finalize_kernel(const double* __restrict__ partials, int n,
                                float* __restrict__ loss_out) {
    __shared__ double sm[256];
    double s = 0.0;
    for (int i = threadIdx.x; i < n; i += 256) s += partials[i];
    sm[threadIdx.x] = s;
    __syncthreads();
    for (int st = 128; st; st >>= 1) {
        if (threadIdx.x < st) sm[threadIdx.x] += sm[threadIdx.x + st];
        __syncthreads();
    }
    if (threadIdx.x == 0)
        *loss_out = (float)(1.25 * sm[0] / (double)((size_t)B_N * D_N));
}

extern "C" void kernel_launch(void* const* d_in, const int* in_sizes, int n_in,
                              void* d_out, int out_size, void* d_ws, size_t ws_size,
                              hipStream_t stream) {
    const float* X = (const float*)d_in[0];
    const float* E = (const float*)d_in[1];
    float* out = (float*)d_out;
    char* ws = (char*)d_ws;

    u16*    Xsw      = (u16*)d_out;          // 16 MiB scratch in d_out (overwritten by rescore)
    float4* top2     = (float4*)(ws + P_TOP2);
    u16*    Esw      = (u16*)(ws + P_ESW);
    float*  en2f     = (float*)(ws + P_EN2);
    double* partials = (double*)(ws + P_PART);

    xconv_kernel<<<(B_N * 32) / 256, 256, 0, stream>>>(X, Xsw);
    econv_kernel<<<(K_N * 32) / 256, 256, 0, stream>>>(E, Esw);
    en2_kernel<<<K_N / 4, 256, 0, stream>>>(E, en2f);
    dist10_kernel<<<B_N / 64, 256, 0, stream>>>(
        (const char*)Xsw, (const char*)Esw, en2f, top2);
    rescore_kernel<<<512, 256, 0, stream>>>(X, E, top2, out, partials);
    finalize_kernel<<<1, 256, 0, stream>>>(partials, 512, out + (size_t)B_N * D_N);
}